// Round 13
// baseline (114.645 us; speedup 1.0000x reference)
//
#include <hip/hip_runtime.h>
#include <hip/hip_bf16.h>

#define B_ 8
#define S_ 4096
#define Q_ 4096
#define D_ 64

typedef __attribute__((ext_vector_type(8))) short short8;
typedef __attribute__((ext_vector_type(4))) float f32x4;

__device__ __forceinline__ unsigned short f2bf(float f) {
  union { float f; unsigned u; } v; v.f = f;
  unsigned u = v.u;
  u += 0x7FFFu + ((u >> 16) & 1u);   // RNE (no NaN in inputs)
  return (unsigned short)(u >> 16);
}

// Convert query to bf16; convert support to bf16 PRE-SCALED by its rsqrt
// magnitude (folds the cosine normalization into the operand).
__global__ void prep_kernel(const float* __restrict__ supp,
                            const float* __restrict__ query,
                            unsigned short* __restrict__ supp_bf,
                            unsigned short* __restrict__ query_bf) {
  int r = blockIdx.x * blockDim.x + threadIdx.x;
  const int nsupp = B_ * S_;
  const int total = nsupp + B_ * Q_;
  if (r >= total) return;
  const bool is_supp = r < nsupp;
  const float* src = is_supp ? (supp + (size_t)r * D_)
                             : (query + (size_t)(r - nsupp) * D_);
  unsigned short* dst = is_supp ? (supp_bf + (size_t)r * D_)
                                : (query_bf + (size_t)(r - nsupp) * D_);
  float4 v[D_ / 4];
  float sum = 0.f;
#pragma unroll
  for (int i = 0; i < D_ / 4; ++i) {
    v[i] = ((const float4*)src)[i];
    sum += v[i].x * v[i].x + v[i].y * v[i].y + v[i].z * v[i].z + v[i].w * v[i].w;
  }
  const float sc = is_supp ? rsqrtf(fmaxf(sum, 1e-10f)) : 1.0f;
#pragma unroll
  for (int i = 0; i < D_ / 4; ++i) {
    ushort4 h;
    h.x = f2bf(v[i].x * sc); h.y = f2bf(v[i].y * sc);
    h.z = f2bf(v[i].z * sc); h.w = f2bf(v[i].w * sc);
    ((ushort4*)dst)[i] = h;
  }
}

// Branchless sorted-descending top-5 insert: 9 min/max ops.
__device__ __forceinline__ void ins5(float (&t)[5], float v) {
  float a = v, b;
  b = fminf(t[0], a); t[0] = fmaxf(t[0], a); a = b;
  b = fminf(t[1], a); t[1] = fmaxf(t[1], a); a = b;
  b = fminf(t[2], a); t[2] = fmaxf(t[2], a); a = b;
  b = fminf(t[3], a); t[3] = fmaxf(t[3], a); a = b;
  t[4] = fmaxf(t[4], a);
}

// LDS-ordering-only barrier (R11): ds ops drained, global stores in flight.
__device__ __forceinline__ void lds_barrier() {
  asm volatile("s_waitcnt lgkmcnt(0)" ::: "memory");
  __builtin_amdgcn_s_barrier();
}

// LOAD-BALANCED roles: every block processes exactly 8 tiles.
//   roles 0..3 : quarter of topk tiles each -> partial top5 to workspace
//   roles 4..7 : quarter of copy tiles each -> R11 elds 256B-run epilogue
__global__ void cos_topk_kernel(const unsigned short* __restrict__ supp_bf,
                                const unsigned short* __restrict__ query_bf,
                                const int* __restrict__ pbshot,
                                float* __restrict__ partials,
                                float* __restrict__ out) {
  const int bs = *pbshot;
  const int OW = 5 + S_ - bs;  // output row width

  const int b  = blockIdx.x >> 6;
  const int q0 = (blockIdx.x & 63) * 64;
  const int tid  = threadIdx.x;
  const int w    = tid >> 6;
  const int lane = tid & 63;
  const int l15  = lane & 15;
  const int l4   = lane >> 4;

  const int nt_top = bs >> 6;        // topk tiles (32)
  const int NT = S_ >> 6;            // all tiles (64)
  const int role = blockIdx.y;
  const bool is_top = (role < 4);
  int t0, t1;
  if (is_top) {
    t0 = (nt_top * role) / 4;
    t1 = (nt_top * (role + 1)) / 4;
  } else {
    const int ct = NT - nt_top;
    t0 = nt_top + (ct * (role - 4)) / 4;
    t1 = nt_top + (ct * (role - 3)) / 4;
  }

  __shared__ unsigned short lds[2][64 * 64];  // staging: 2 x 8 KB, swizzled
  __shared__ float elds[4][16][65];           // epilogue transpose, per-wave

  // --- A fragments: this wave's 16 query rows, K=64, held in regs ---
  // A layout (16x16x32): row = lane&15, k = (lane>>4)*8 + j
  const int qrow = q0 + w * 16 + l15;
  const unsigned short* qbase = query_bf + (size_t)(b * Q_ + qrow) * D_;
  const short8 a0 = *(const short8*)(qbase + l4 * 8);
  const short8 a1 = *(const short8*)(qbase + 32 + l4 * 8);

  float tk[4][5];
#pragma unroll
  for (int r2 = 0; r2 < 4; ++r2)
#pragma unroll
    for (int j = 0; j < 5; ++j) tk[r2][j] = -INFINITY;

  // --- staging (register path): 256 threads x 32B = one 8 KB tile ---
  const int srow  = tid >> 2;   // support row within tile
  const int chunk = tid & 3;    // 16-ushort chunk
  const unsigned short* gstage0 =
      supp_bf + ((size_t)b * S_ + srow) * D_ + chunk * 16;
  // swizzle invariant: LDS[r][c8] = G[r][c8 ^ (r&7)] in 8-ushort chunks
  const int dsw0 = srow * 64 + ((chunk * 16 + 0) ^ ((srow & 7) << 3));
  const int dsw1 = srow * 64 + ((chunk * 16 + 8) ^ ((srow & 7) << 3));

  uint4 st0 = *(const uint4*)(gstage0 + (size_t)t0 * 64 * D_);
  uint4 st1 = *(const uint4*)(gstage0 + (size_t)t0 * 64 * D_ + 8);
  *(uint4*)&lds[0][dsw0] = st0;
  *(uint4*)&lds[0][dsw1] = st1;

  const int rbase = b * Q_ + q0 + w * 16 + l4 * 4;        // top-k row base
  // copy-role epilogue base: wave's first q-row; col = t*64 + lane
  float* owave = out + (size_t)(b * Q_ + q0 + w * 16) * OW + 5 - bs;

  for (int t = t0; t < t1; ++t) {
    const int buf = (t - t0) & 1;
    if (t + 1 < t1) {  // issue next tile's global loads early (hide HBM lat)
      const unsigned short* g = gstage0 + (size_t)(t + 1) * 64 * D_;
      st0 = *(const uint4*)(g);
      st1 = *(const uint4*)(g + 8);
    }
    lds_barrier();     // tile t's ds_writes visible; stores stay in flight

    f32x4 ab[4];       // per-fc results (fully unrolled -> registers)
#pragma unroll
    for (int fc = 0; fc < 4; ++fc) {
      // B layout (16x16x32): col = lane&15, k = (lane>>4)*8 + j
      const int scol = fc * 16 + l15;  // support row within LDS tile
      const int idx0 = scol * 64 + ((l4 * 8) ^ ((scol & 7) << 3));
      const int idx1 = scol * 64 + ((32 + l4 * 8) ^ ((scol & 7) << 3));
      const short8 b0 = *(const short8*)&lds[buf][idx0];
      const short8 b1 = *(const short8*)&lds[buf][idx1];
      f32x4 acc = {0.f, 0.f, 0.f, 0.f};
      acc = __builtin_amdgcn_mfma_f32_16x16x32_bf16(a0, b0, acc, 0, 0, 0);
      acc = __builtin_amdgcn_mfma_f32_16x16x32_bf16(a1, b1, acc, 0, 0, 0);

      if (is_top) {
#pragma unroll
        for (int r2 = 0; r2 < 4; ++r2) ins5(tk[r2], acc[r2]);
      } else {
        ab[fc] = acc;
      }
    }

    if (!is_top) {
      // per-wave transpose: [q-row within 16][s-col within 64]
#pragma unroll
      for (int fc = 0; fc < 4; ++fc)
#pragma unroll
        for (int r2 = 0; r2 < 4; ++r2)
          elds[w][l4 * 4 + r2][fc * 16 + l15] = ab[fc][r2];
      // same-wave LDS dependency -> compiler emits lgkmcnt wait
#pragma unroll
      for (int i = 0; i < 16; ++i) {
        const float vv = elds[w][i][lane];
        owave[(size_t)i * OW + t * 64 + lane] = vv;  // 256 B contiguous/inst
      }
    }

    if (t + 1 < t1) {  // write next tile into the other buffer
      *(uint4*)&lds[buf ^ 1][dsw0] = st0;
      *(uint4*)&lds[buf ^ 1][dsw1] = st1;
    }
  }

  if (is_top) {
    // butterfly merge of top-5 across the 16 lanes sharing each row
#pragma unroll
    for (int m = 1; m <= 8; m <<= 1) {
#pragma unroll
      for (int r2 = 0; r2 < 4; ++r2) {
        float o0 = __shfl_xor(tk[r2][0], m);
        float o1 = __shfl_xor(tk[r2][1], m);
        float o2 = __shfl_xor(tk[r2][2], m);
        float o3 = __shfl_xor(tk[r2][3], m);
        float o4 = __shfl_xor(tk[r2][4], m);
        ins5(tk[r2], o0); ins5(tk[r2], o1); ins5(tk[r2], o2);
        ins5(tk[r2], o3); ins5(tk[r2], o4);
      }
    }
    if (l15 == 0) {
      // partial top5 of this role's 8-tile slice -> workspace
#pragma unroll
      for (int r2 = 0; r2 < 4; ++r2) {
        float* op = partials + (size_t)(rbase + r2) * 20 + role * 5;
        op[0] = tk[r2][0]; op[1] = tk[r2][1]; op[2] = tk[r2][2];
        op[3] = tk[r2][3]; op[4] = tk[r2][4];
      }
    }
  }
}

// Merge 4 sorted partial top-5 lists per row -> final top-5.
__global__ void topk_merge_kernel(const float* __restrict__ partials,
                                  const int* __restrict__ pbshot,
                                  float* __restrict__ out) {
  const int bs = *pbshot;
  const int OW = 5 + S_ - bs;
  int r = blockIdx.x * blockDim.x + threadIdx.x;
  if (r >= B_ * Q_) return;
  const float* p = partials + (size_t)r * 20;
  float tk[5] = {p[0], p[1], p[2], p[3], p[4]};
#pragma unroll
  for (int j = 5; j < 20; ++j) ins5(tk, p[j]);
  float* op = out + (size_t)r * OW;
  op[0] = tk[0]; op[1] = tk[1]; op[2] = tk[2]; op[3] = tk[3]; op[4] = tk[4];
}

extern "C" void kernel_launch(void* const* d_in, const int* in_sizes, int n_in,
                              void* d_out, int out_size, void* d_ws, size_t ws_size,
                              hipStream_t stream) {
  const float* supp  = (const float*)d_in[0];
  const float* query = (const float*)d_in[1];
  const int* pbshot  = (const int*)d_in[2];
  float* out = (float*)d_out;

  unsigned short* supp_bf  = (unsigned short*)d_ws;                  // 4 MB
  unsigned short* query_bf = supp_bf + (size_t)B_ * S_ * D_;         // 4 MB
  float* partials = (float*)(query_bf + (size_t)B_ * Q_ * D_);       // 2.6 MB

  const int rows = B_ * (S_ + Q_);
  prep_kernel<<<(rows + 255) / 256, 256, 0, stream>>>(supp, query, supp_bf,
                                                      query_bf);
  dim3 grid(B_ * (Q_ / 64), 8);
  cos_topk_kernel<<<grid, 256, 0, stream>>>(supp_bf, query_bf, pbshot,
                                            partials, out);
  topk_merge_kernel<<<(B_ * Q_ + 255) / 256, 256, 0, stream>>>(partials,
                                                               pbshot, out);
}

// Round 14
// 82.548 us; speedup vs baseline: 1.3888x; 1.3888x over previous
//
#include <hip/hip_runtime.h>
#include <hip/hip_bf16.h>

#define B_ 8
#define S_ 4096
#define Q_ 4096
#define D_ 64

typedef __attribute__((ext_vector_type(8))) short short8;
typedef __attribute__((ext_vector_type(4))) float f32x4;

__device__ __forceinline__ unsigned short f2bf(float f) {
  union { float f; unsigned u; } v; v.f = f;
  unsigned u = v.u;
  u += 0x7FFFu + ((u >> 16) & 1u);   // RNE (no NaN in inputs)
  return (unsigned short)(u >> 16);
}

// Convert query to bf16; convert support to bf16 PRE-SCALED by its rsqrt
// magnitude (folds the cosine normalization into the operand).
__global__ void prep_kernel(const float* __restrict__ supp,
                            const float* __restrict__ query,
                            unsigned short* __restrict__ supp_bf,
                            unsigned short* __restrict__ query_bf) {
  int r = blockIdx.x * blockDim.x + threadIdx.x;
  const int nsupp = B_ * S_;
  const int total = nsupp + B_ * Q_;
  if (r >= total) return;
  const bool is_supp = r < nsupp;
  const float* src = is_supp ? (supp + (size_t)r * D_)
                             : (query + (size_t)(r - nsupp) * D_);
  unsigned short* dst = is_supp ? (supp_bf + (size_t)r * D_)
                                : (query_bf + (size_t)(r - nsupp) * D_);
  float4 v[D_ / 4];
  float sum = 0.f;
#pragma unroll
  for (int i = 0; i < D_ / 4; ++i) {
    v[i] = ((const float4*)src)[i];
    sum += v[i].x * v[i].x + v[i].y * v[i].y + v[i].z * v[i].z + v[i].w * v[i].w;
  }
  const float sc = is_supp ? rsqrtf(fmaxf(sum, 1e-10f)) : 1.0f;
#pragma unroll
  for (int i = 0; i < D_ / 4; ++i) {
    ushort4 h;
    h.x = f2bf(v[i].x * sc); h.y = f2bf(v[i].y * sc);
    h.z = f2bf(v[i].z * sc); h.w = f2bf(v[i].w * sc);
    ((ushort4*)dst)[i] = h;
  }
}

// Branchless sorted-descending top-5 insert: 9 min/max ops.
__device__ __forceinline__ void ins5(float (&t)[5], float v) {
  float a = v, b;
  b = fminf(t[0], a); t[0] = fmaxf(t[0], a); a = b;
  b = fminf(t[1], a); t[1] = fmaxf(t[1], a); a = b;
  b = fminf(t[2], a); t[2] = fmaxf(t[2], a); a = b;
  b = fminf(t[3], a); t[3] = fmaxf(t[3], a); a = b;
  t[4] = fmaxf(t[4], a);
}

// LDS-ordering-only barrier (R11): ds ops drained, global stores in flight.
__device__ __forceinline__ void lds_barrier() {
  asm volatile("s_waitcnt lgkmcnt(0)" ::: "memory");
  __builtin_amdgcn_s_barrier();
}

// R11 structure + XCD-aware block swizzle: bx = ((x&7)<<6)|(x>>3) makes
// batch == x&7 == XCD id (512 blocks/role, dispatch round-robins x over 8
// XCDs). Each XCD L2 then holds ONE batch's support+query (1 MB) instead of
// all 8 (4 MB + output stream evictions) -> the ~263 MB of support re-reads
// become L2 hits instead of HBM re-fetches.
__global__ void cos_topk_kernel(const unsigned short* __restrict__ supp_bf,
                                const unsigned short* __restrict__ query_bf,
                                const int* __restrict__ pbshot,
                                float* __restrict__ out) {
  const int bs = *pbshot;
  const int OW = 5 + S_ - bs;  // output row width

  const int x  = blockIdx.x;
  const int b  = x & 7;                  // batch == XCD id
  const int q0 = (x >> 3) * 64;
  const int tid  = threadIdx.x;
  const int w    = tid >> 6;
  const int lane = tid & 63;
  const int l15  = lane & 15;
  const int l4   = lane >> 4;

  const int nt_top = bs >> 6;
  const int role = blockIdx.y;
  const bool is_top = (role == 0);
  int t0, t1;
  if (is_top) { t0 = 0; t1 = nt_top; }
  else {
    const int ct = (S_ >> 6) - nt_top;
    t0 = nt_top + (ct * (role - 1)) / 6;
    t1 = nt_top + (ct * role) / 6;
  }

  __shared__ unsigned short lds[2][64 * 64];  // staging: 2 x 8 KB, swizzled
  __shared__ float elds[4][16][65];           // epilogue transpose, per-wave

  // --- A fragments: this wave's 16 query rows, K=64, held in regs ---
  // A layout (16x16x32): row = lane&15, k = (lane>>4)*8 + j
  const int qrow = q0 + w * 16 + l15;
  const unsigned short* qbase = query_bf + (size_t)(b * Q_ + qrow) * D_;
  const short8 a0 = *(const short8*)(qbase + l4 * 8);
  const short8 a1 = *(const short8*)(qbase + 32 + l4 * 8);

  float tk[4][5];
#pragma unroll
  for (int r2 = 0; r2 < 4; ++r2)
#pragma unroll
    for (int j = 0; j < 5; ++j) tk[r2][j] = -INFINITY;

  // --- staging (register path): 256 threads x 32B = one 8 KB tile ---
  const int srow  = tid >> 2;   // support row within tile
  const int chunk = tid & 3;    // 16-ushort chunk
  const unsigned short* gstage0 =
      supp_bf + ((size_t)b * S_ + srow) * D_ + chunk * 16;
  // swizzle invariant: LDS[r][c8] = G[r][c8 ^ (r&7)] in 8-ushort chunks
  const int dsw0 = srow * 64 + ((chunk * 16 + 0) ^ ((srow & 7) << 3));
  const int dsw1 = srow * 64 + ((chunk * 16 + 8) ^ ((srow & 7) << 3));

  uint4 st0 = *(const uint4*)(gstage0 + (size_t)t0 * 64 * D_);
  uint4 st1 = *(const uint4*)(gstage0 + (size_t)t0 * 64 * D_ + 8);
  *(uint4*)&lds[0][dsw0] = st0;
  *(uint4*)&lds[0][dsw1] = st1;

  const int rbase = b * Q_ + q0 + w * 16 + l4 * 4;        // top-k row base
  // copy-role epilogue base: wave's first q-row; col = t*64 + lane
  float* owave = out + (size_t)(b * Q_ + q0 + w * 16) * OW + 5 - bs;

  for (int t = t0; t < t1; ++t) {
    const int buf = (t - t0) & 1;
    if (t + 1 < t1) {  // issue next tile's global loads early (hide HBM lat)
      const unsigned short* g = gstage0 + (size_t)(t + 1) * 64 * D_;
      st0 = *(const uint4*)(g);
      st1 = *(const uint4*)(g + 8);
    }
    lds_barrier();     // tile t's ds_writes visible; stores stay in flight

    f32x4 ab[4];       // per-fc results (fully unrolled -> registers)
#pragma unroll
    for (int fc = 0; fc < 4; ++fc) {
      // B layout (16x16x32): col = lane&15, k = (lane>>4)*8 + j
      const int scol = fc * 16 + l15;  // support row within LDS tile
      const int idx0 = scol * 64 + ((l4 * 8) ^ ((scol & 7) << 3));
      const int idx1 = scol * 64 + ((32 + l4 * 8) ^ ((scol & 7) << 3));
      const short8 b0 = *(const short8*)&lds[buf][idx0];
      const short8 b1 = *(const short8*)&lds[buf][idx1];
      f32x4 acc = {0.f, 0.f, 0.f, 0.f};
      acc = __builtin_amdgcn_mfma_f32_16x16x32_bf16(a0, b0, acc, 0, 0, 0);
      acc = __builtin_amdgcn_mfma_f32_16x16x32_bf16(a1, b1, acc, 0, 0, 0);

      if (is_top) {
#pragma unroll
        for (int r2 = 0; r2 < 4; ++r2) ins5(tk[r2], acc[r2]);
      } else {
        ab[fc] = acc;
      }
    }

    if (!is_top) {
      // per-wave transpose: [q-row within 16][s-col within 64]
#pragma unroll
      for (int fc = 0; fc < 4; ++fc)
#pragma unroll
        for (int r2 = 0; r2 < 4; ++r2)
          elds[w][l4 * 4 + r2][fc * 16 + l15] = ab[fc][r2];
      // same-wave LDS dependency -> compiler emits lgkmcnt wait
#pragma unroll
      for (int i = 0; i < 16; ++i) {
        const float vv = elds[w][i][lane];
        owave[(size_t)i * OW + t * 64 + lane] = vv;  // 256 B contiguous/inst
      }
    }

    if (t + 1 < t1) {  // write next tile into the other buffer
      *(uint4*)&lds[buf ^ 1][dsw0] = st0;
      *(uint4*)&lds[buf ^ 1][dsw1] = st1;
    }
  }

  if (is_top) {
    // butterfly merge of top-5 across the 16 lanes sharing each row
#pragma unroll
    for (int m = 1; m <= 8; m <<= 1) {
#pragma unroll
      for (int r2 = 0; r2 < 4; ++r2) {
        float o0 = __shfl_xor(tk[r2][0], m);
        float o1 = __shfl_xor(tk[r2][1], m);
        float o2 = __shfl_xor(tk[r2][2], m);
        float o3 = __shfl_xor(tk[r2][3], m);
        float o4 = __shfl_xor(tk[r2][4], m);
        ins5(tk[r2], o0); ins5(tk[r2], o1); ins5(tk[r2], o2);
        ins5(tk[r2], o3); ins5(tk[r2], o4);
      }
    }
    if (l15 == 0) {
#pragma unroll
      for (int r2 = 0; r2 < 4; ++r2) {
        float* op = out + (size_t)(rbase + r2) * OW;
        op[0] = tk[r2][0]; op[1] = tk[r2][1]; op[2] = tk[r2][2];
        op[3] = tk[r2][3]; op[4] = tk[r2][4];
      }
    }
  }
}

extern "C" void kernel_launch(void* const* d_in, const int* in_sizes, int n_in,
                              void* d_out, int out_size, void* d_ws, size_t ws_size,
                              hipStream_t stream) {
  const float* supp  = (const float*)d_in[0];
  const float* query = (const float*)d_in[1];
  const int* pbshot  = (const int*)d_in[2];
  float* out = (float*)d_out;

  unsigned short* supp_bf  = (unsigned short*)d_ws;
  unsigned short* query_bf = supp_bf + (size_t)B_ * S_ * D_;

  const int rows = B_ * (S_ + Q_);
  prep_kernel<<<(rows + 255) / 256, 256, 0, stream>>>(supp, query, supp_bf,
                                                      query_bf);
  dim3 grid(B_ * (Q_ / 64), 7);
  cos_topk_kernel<<<grid, 256, 0, stream>>>(supp_bf, query_bf, pbshot, out);
}

// Round 15
// 80.772 us; speedup vs baseline: 1.4194x; 1.0220x over previous
//
#include <hip/hip_runtime.h>
#include <hip/hip_bf16.h>

#define B_ 8
#define S_ 4096
#define Q_ 4096
#define D_ 64

typedef __attribute__((ext_vector_type(8))) short short8;
typedef __attribute__((ext_vector_type(4))) float f32x4;
typedef __attribute__((ext_vector_type(4), aligned(4))) float f32x4u;

__device__ __forceinline__ unsigned short f2bf(float f) {
  union { float f; unsigned u; } v; v.f = f;
  unsigned u = v.u;
  u += 0x7FFFu + ((u >> 16) & 1u);   // RNE (no NaN in inputs)
  return (unsigned short)(u >> 16);
}

// Convert query to bf16; convert support to bf16 PRE-SCALED by its rsqrt
// magnitude (folds the cosine normalization into the operand).
__global__ void prep_kernel(const float* __restrict__ supp,
                            const float* __restrict__ query,
                            unsigned short* __restrict__ supp_bf,
                            unsigned short* __restrict__ query_bf) {
  int r = blockIdx.x * blockDim.x + threadIdx.x;
  const int nsupp = B_ * S_;
  const int total = nsupp + B_ * Q_;
  if (r >= total) return;
  const bool is_supp = r < nsupp;
  const float* src = is_supp ? (supp + (size_t)r * D_)
                             : (query + (size_t)(r - nsupp) * D_);
  unsigned short* dst = is_supp ? (supp_bf + (size_t)r * D_)
                                : (query_bf + (size_t)(r - nsupp) * D_);
  float4 v[D_ / 4];
  float sum = 0.f;
#pragma unroll
  for (int i = 0; i < D_ / 4; ++i) {
    v[i] = ((const float4*)src)[i];
    sum += v[i].x * v[i].x + v[i].y * v[i].y + v[i].z * v[i].z + v[i].w * v[i].w;
  }
  const float sc = is_supp ? rsqrtf(fmaxf(sum, 1e-10f)) : 1.0f;
#pragma unroll
  for (int i = 0; i < D_ / 4; ++i) {
    ushort4 h;
    h.x = f2bf(v[i].x * sc); h.y = f2bf(v[i].y * sc);
    h.z = f2bf(v[i].z * sc); h.w = f2bf(v[i].w * sc);
    ((ushort4*)dst)[i] = h;
  }
}

// Branchless sorted-descending top-5 insert: 9 min/max ops.
__device__ __forceinline__ void ins5(float (&t)[5], float v) {
  float a = v, b;
  b = fminf(t[0], a); t[0] = fmaxf(t[0], a); a = b;
  b = fminf(t[1], a); t[1] = fmaxf(t[1], a); a = b;
  b = fminf(t[2], a); t[2] = fmaxf(t[2], a); a = b;
  b = fminf(t[3], a); t[3] = fmaxf(t[3], a); a = b;
  t[4] = fmaxf(t[4], a);
}

// LDS-ordering-only barrier (R11): ds ops drained, global stores in flight.
__device__ __forceinline__ void lds_barrier() {
  asm volatile("s_waitcnt lgkmcnt(0)" ::: "memory");
  __builtin_amdgcn_s_barrier();
}

// R14 (XCD swizzle: batch == x&7 == XCD id) + vectorized copy epilogue:
// elds stride 68 floats (272 B = 17x16 -> b128-aligned rows); read back 4
// consecutive cols/lane via ds_read_b128 (4 instr, was 16 b32) and store
// one aligned(4) f32x4 per 4 rows (4 store instr, was 16 dwords).
__global__ void cos_topk_kernel(const unsigned short* __restrict__ supp_bf,
                                const unsigned short* __restrict__ query_bf,
                                const int* __restrict__ pbshot,
                                float* __restrict__ out) {
  const int bs = *pbshot;
  const int OW = 5 + S_ - bs;  // output row width

  const int x  = blockIdx.x;
  const int b  = x & 7;                  // batch == XCD id
  const int q0 = (x >> 3) * 64;
  const int tid  = threadIdx.x;
  const int w    = tid >> 6;
  const int lane = tid & 63;
  const int l15  = lane & 15;
  const int l4   = lane >> 4;

  const int nt_top = bs >> 6;
  const int role = blockIdx.y;
  const bool is_top = (role == 0);
  int t0, t1;
  if (is_top) { t0 = 0; t1 = nt_top; }
  else {
    const int ct = (S_ >> 6) - nt_top;
    t0 = nt_top + (ct * (role - 1)) / 6;
    t1 = nt_top + (ct * role) / 6;
  }

  __shared__ unsigned short lds[2][64 * 64];  // staging: 2 x 8 KB, swizzled
  __shared__ float elds[4][16][68];           // epilogue transpose, per-wave

  // --- A fragments: this wave's 16 query rows, K=64, held in regs ---
  // A layout (16x16x32): row = lane&15, k = (lane>>4)*8 + j
  const int qrow = q0 + w * 16 + l15;
  const unsigned short* qbase = query_bf + (size_t)(b * Q_ + qrow) * D_;
  const short8 a0 = *(const short8*)(qbase + l4 * 8);
  const short8 a1 = *(const short8*)(qbase + 32 + l4 * 8);

  float tk[4][5];
#pragma unroll
  for (int r2 = 0; r2 < 4; ++r2)
#pragma unroll
    for (int j = 0; j < 5; ++j) tk[r2][j] = -INFINITY;

  // --- staging (register path): 256 threads x 32B = one 8 KB tile ---
  const int srow  = tid >> 2;   // support row within tile
  const int chunk = tid & 3;    // 16-ushort chunk
  const unsigned short* gstage0 =
      supp_bf + ((size_t)b * S_ + srow) * D_ + chunk * 16;
  // swizzle invariant: LDS[r][c8] = G[r][c8 ^ (r&7)] in 8-ushort chunks
  const int dsw0 = srow * 64 + ((chunk * 16 + 0) ^ ((srow & 7) << 3));
  const int dsw1 = srow * 64 + ((chunk * 16 + 8) ^ ((srow & 7) << 3));

  uint4 st0 = *(const uint4*)(gstage0 + (size_t)t0 * 64 * D_);
  uint4 st1 = *(const uint4*)(gstage0 + (size_t)t0 * 64 * D_ + 8);
  *(uint4*)&lds[0][dsw0] = st0;
  *(uint4*)&lds[0][dsw1] = st1;

  const int rbase = b * Q_ + q0 + w * 16 + l4 * 4;        // top-k row base
  // copy-role epilogue base: wave's first q-row
  float* owave = out + (size_t)(b * Q_ + q0 + w * 16) * OW + 5 - bs;

  for (int t = t0; t < t1; ++t) {
    const int buf = (t - t0) & 1;
    if (t + 1 < t1) {  // issue next tile's global loads early (hide HBM lat)
      const unsigned short* g = gstage0 + (size_t)(t + 1) * 64 * D_;
      st0 = *(const uint4*)(g);
      st1 = *(const uint4*)(g + 8);
    }
    lds_barrier();     // tile t's ds_writes visible; stores stay in flight

    f32x4 ab[4];       // per-fc results (fully unrolled -> registers)
#pragma unroll
    for (int fc = 0; fc < 4; ++fc) {
      // B layout (16x16x32): col = lane&15, k = (lane>>4)*8 + j
      const int scol = fc * 16 + l15;  // support row within LDS tile
      const int idx0 = scol * 64 + ((l4 * 8) ^ ((scol & 7) << 3));
      const int idx1 = scol * 64 + ((32 + l4 * 8) ^ ((scol & 7) << 3));
      const short8 b0 = *(const short8*)&lds[buf][idx0];
      const short8 b1 = *(const short8*)&lds[buf][idx1];
      f32x4 acc = {0.f, 0.f, 0.f, 0.f};
      acc = __builtin_amdgcn_mfma_f32_16x16x32_bf16(a0, b0, acc, 0, 0, 0);
      acc = __builtin_amdgcn_mfma_f32_16x16x32_bf16(a1, b1, acc, 0, 0, 0);

      if (is_top) {
#pragma unroll
        for (int r2 = 0; r2 < 4; ++r2) ins5(tk[r2], acc[r2]);
      } else {
        ab[fc] = acc;
      }
    }

    if (!is_top) {
      // per-wave transpose write: [q-row within 16][s-col within 64]
#pragma unroll
      for (int fc = 0; fc < 4; ++fc)
#pragma unroll
        for (int r2 = 0; r2 < 4; ++r2)
          elds[w][l4 * 4 + r2][fc * 16 + l15] = ab[fc][r2];
      // vector read-back: 4 rows per pass, 4 consecutive cols per lane
#pragma unroll
      for (int pass = 0; pass < 4; ++pass) {
        const int i  = pass * 4 + l4;        // q-row within 16
        const int cc = l15 * 4;              // col group
        const f32x4 vv = *(const f32x4*)&elds[w][i][cc];   // ds_read_b128
        *(f32x4u*)(owave + (size_t)i * OW + t * 64 + cc) = vv;
      }
    }

    if (t + 1 < t1) {  // write next tile into the other buffer
      *(uint4*)&lds[buf ^ 1][dsw0] = st0;
      *(uint4*)&lds[buf ^ 1][dsw1] = st1;
    }
  }

  if (is_top) {
    // butterfly merge of top-5 across the 16 lanes sharing each row
#pragma unroll
    for (int m = 1; m <= 8; m <<= 1) {
#pragma unroll
      for (int r2 = 0; r2 < 4; ++r2) {
        float o0 = __shfl_xor(tk[r2][0], m);
        float o1 = __shfl_xor(tk[r2][1], m);
        float o2 = __shfl_xor(tk[r2][2], m);
        float o3 = __shfl_xor(tk[r2][3], m);
        float o4 = __shfl_xor(tk[r2][4], m);
        ins5(tk[r2], o0); ins5(tk[r2], o1); ins5(tk[r2], o2);
        ins5(tk[r2], o3); ins5(tk[r2], o4);
      }
    }
    if (l15 == 0) {
#pragma unroll
      for (int r2 = 0; r2 < 4; ++r2) {
        float* op = out + (size_t)(rbase + r2) * OW;
        op[0] = tk[r2][0]; op[1] = tk[r2][1]; op[2] = tk[r2][2];
        op[3] = tk[r2][3]; op[4] = tk[r2][4];
      }
    }
  }
}

extern "C" void kernel_launch(void* const* d_in, const int* in_sizes, int n_in,
                              void* d_out, int out_size, void* d_ws, size_t ws_size,
                              hipStream_t stream) {
  const float* supp  = (const float*)d_in[0];
  const float* query = (const float*)d_in[1];
  const int* pbshot  = (const int*)d_in[2];
  float* out = (float*)d_out;

  unsigned short* supp_bf  = (unsigned short*)d_ws;
  unsigned short* query_bf = supp_bf + (size_t)B_ * S_ * D_;

  const int rows = B_ * (S_ + Q_);
  prep_kernel<<<(rows + 255) / 256, 256, 0, stream>>>(supp, query, supp_bf,
                                                      query_bf);
  dim3 grid(B_ * (Q_ / 64), 7);
  cos_topk_kernel<<<grid, 256, 0, stream>>>(supp_bf, query_bf, pbshot, out);
}